// Round 5
// baseline (119.915 us; speedup 1.0000x reference)
//
#include <hip/hip_runtime.h>
#include <hip/hip_bf16.h>

typedef __bf16 bf16_t;
typedef bf16_t bf16x8 __attribute__((ext_vector_type(8)));
typedef bf16_t bf16x4 __attribute__((ext_vector_type(4)));
typedef float  floatx4 __attribute__((ext_vector_type(4)));

#define NROWS 65536
#define NCENT 512
#define NDIM  128

// d_ws: [0,131072) mu bf16 frag-major; [131072,133120) h2 = 0.5*|mu_bf16|^2 float[512]
// frag-major addr(col,k) = jg*2048 + kk*512 + quad*128 + l16*8 + e
//   col = jg*16 + l16, k = kk*32 + quad*8 + e
// -> a wave's B-frag b128 load (lane=(l16,quad)) is 1KB lane-contiguous: perfectly coalesced.

__global__ __launch_bounds__(256)
void mu_pack_kernel(const float* __restrict__ mu, bf16_t* __restrict__ ws_mu,
                    float* __restrict__ ws_h2)
{
    const int tid = threadIdx.x;
    const int col_local = tid >> 5;     // 8 cols per block
    const int j = tid & 31;             // 32 threads per col, 4 floats each
    const int col = blockIdx.x * 8 + col_local;
    const float4 v = *(const float4*)(mu + col * NDIM + j * 4);
    bf16x4 pk = {(bf16_t)v.x, (bf16_t)v.y, (bf16_t)v.z, (bf16_t)v.w};
    const int k0 = j * 4;
    const int kk = k0 >> 5, quad = (k0 >> 3) & 3, e0 = k0 & 7;
    const int jg = col >> 4, c16 = col & 15;
    *(bf16x4*)(ws_mu + jg*2048 + kk*512 + quad*128 + c16*8 + e0) = pk;
    float f0=(float)pk[0], f1=(float)pk[1], f2=(float)pk[2], f3=(float)pk[3];
    float s = f0*f0 + f1*f1 + f2*f2 + f3*f3;
    s += __shfl_xor(s, 1);  s += __shfl_xor(s, 2);  s += __shfl_xor(s, 4);
    s += __shfl_xor(s, 8);  s += __shfl_xor(s, 16);
    if (j == 0) ws_h2[col] = 0.5f * s;
}

__global__ __launch_bounds__(128, 2)
void kmeans_main(const float* __restrict__ z, const bf16_t* __restrict__ ws_mu,
                 const float* __restrict__ ws_h2, float* __restrict__ out)
{
    __shared__ float rmx[2][64];    // per col-half row maxes
    __shared__ float z2row[64];     // 768 B total LDS; ONE barrier in the kernel

    const int tid  = threadIdx.x;
    const int lane = tid & 63;
    const int w    = tid >> 6;      // col-half: wave w covers cols w*256 .. w*256+255
    const int quad = lane >> 4;
    const int l16  = lane & 15;
    const size_t rowbase = (size_t)blockIdx.x * 64;

    // ---- A fragments: 64 rows straight from global fp32, cvt to bf16 in regs ----
    // lane (l16,quad), set i: row = rowbase + i*16 + l16, elems k = kk*32+quad*8+e
    bf16x8 afr[4][4];
    float  z2c[4][4];               // z2 in C-layout: [set][r] for row = i*16+quad*4+r
#pragma unroll
    for (int i = 0; i < 4; ++i) {
        const float* rp = z + (rowbase + i*16 + l16) * NDIM + quad*8;
        float ss = 0.f;
#pragma unroll
        for (int kk = 0; kk < 4; ++kk) {
            float4 a = *(const float4*)(rp + kk*32);
            float4 b = *(const float4*)(rp + kk*32 + 4);
            bf16x8 pk = {(bf16_t)a.x, (bf16_t)a.y, (bf16_t)a.z, (bf16_t)a.w,
                         (bf16_t)b.x, (bf16_t)b.y, (bf16_t)b.z, (bf16_t)b.w};
            afr[i][kk] = pk;
#pragma unroll
            for (int e = 0; e < 8; ++e) { float f = (float)pk[e]; ss = fmaf(f, f, ss); }
        }
        // sum the 4 quad-partials -> z2 of row i*16+l16 (replicated over quads)
        ss += __shfl_xor(ss, 16);
        ss += __shfl_xor(ss, 32);
        // redistribute to C-layout: lane needs z2 of row i*16 + quad*4 + r
#pragma unroll
        for (int r = 0; r < 4; ++r)
            z2c[i][r] = __shfl(ss, quad*4 + r);
    }

    // ---- preload h2 for this wave's 16 col-groups (coalesced, L2-hit) ----
    float h2a[16];
#pragma unroll
    for (int j2 = 0; j2 < 16; ++j2)
        h2a[j2] = ws_h2[(w*16 + j2)*16 + l16];

    // ---- stream B from L2, double-buffered; pure-register MFMA loop ----
    const bf16_t* bbase = ws_mu + (size_t)w*16*2048 + quad*128 + l16*8;
    bf16x8 bb[2][4];
#pragma unroll
    for (int kk = 0; kk < 4; ++kk)
        bb[0][kk] = *(const bf16x8*)(bbase + kk*512);

    float tm[4][4];
#pragma unroll
    for (int i = 0; i < 4; ++i)
#pragma unroll
        for (int r = 0; r < 4; ++r) tm[i][r] = -3.0e38f;

#pragma unroll
    for (int j2 = 0; j2 < 16; ++j2) {
        const int cb = j2 & 1;
        if (j2 < 15) {
            const bf16_t* nb = bbase + (size_t)(j2 + 1)*2048;
#pragma unroll
            for (int kk = 0; kk < 4; ++kk)
                bb[cb ^ 1][kk] = *(const bf16x8*)(nb + kk*512);
        }
        const float mh = -h2a[j2];          // acc-init = -0.5*|mu|^2
#pragma unroll
        for (int i = 0; i < 4; ++i) {       // 4 independent acc chains
            floatx4 acc = (floatx4){mh, mh, mh, mh};
#pragma unroll
            for (int kk = 0; kk < 4; ++kk)
                acc = __builtin_amdgcn_mfma_f32_16x16x32_bf16(
                    afr[i][kk], bb[cb][kk], acc, 0, 0, 0);
#pragma unroll
            for (int r = 0; r < 4; ++r)
                tm[i][r] = fmaxf(tm[i][r], acc[r]);   // max(dot - h2): deferred sqrt
        }
    }

    // ---- reduce tm over the 16 cols per lane-group; publish per col-half ----
#pragma unroll
    for (int i = 0; i < 4; ++i)
#pragma unroll
        for (int r = 0; r < 4; ++r) {
            float v = tm[i][r];
            v = fmaxf(v, __shfl_xor(v, 1));
            v = fmaxf(v, __shfl_xor(v, 2));
            v = fmaxf(v, __shfl_xor(v, 4));
            v = fmaxf(v, __shfl_xor(v, 8));
            if (l16 == 0) {
                rmx[w][i*16 + quad*4 + r] = v;
                if (w == 0) z2row[i*16 + quad*4 + r] = z2c[i][r];
            }
        }
    __syncthreads();   // the only barrier

    // ---- one sqrt per row, block sum, one atomic ----
    if (tid < 64) {
        float m  = fmaxf(rmx[0][tid], rmx[1][tid]);
        float d2 = z2row[tid] - 2.0f * m;
        float v  = sqrtf(fmaxf(d2, 0.f));
#pragma unroll
        for (int off = 32; off; off >>= 1) v += __shfl_down(v, off);
        if (tid == 0) atomicAdd(out, v * (1.0f / 65536.0f));
    }
}

extern "C" void kernel_launch(void* const* d_in, const int* in_sizes, int n_in,
                              void* d_out, int out_size, void* d_ws, size_t ws_size,
                              hipStream_t stream) {
    const float* z  = (const float*)d_in[0];
    const float* mu = (const float*)d_in[1];
    float* out = (float*)d_out;
    bf16_t* ws_mu = (bf16_t*)d_ws;
    float* ws_h2 = (float*)((char*)d_ws + 131072);
    hipMemsetAsync(out, 0, sizeof(float), stream);   // d_out is poisoned 0xAA
    mu_pack_kernel<<<dim3(64), dim3(256), 0, stream>>>(mu, ws_mu, ws_h2);
    kmeans_main<<<dim3(NROWS / 64), dim3(128), 0, stream>>>(z, ws_mu, ws_h2, out);
}